// Round 3
// baseline (859.448 us; speedup 1.0000x reference)
//
#include <hip/hip_runtime.h>
#include <math.h>

#define NN 32768
#define NE 524288

__device__ __forceinline__ float sspf(float x) {
    float r = fmaxf(x, 0.0f) + log1pf(expf(-fabsf(x)));
    return r - 0.69314718055994530942f;
}

// ---------------- CSR build ----------------
__global__ __launch_bounds__(256) void hist_kernel(
    const int* __restrict__ idx_i, int* __restrict__ counts)
{
    int e = blockIdx.x * 256 + threadIdx.x;
    atomicAdd(&counts[idx_i[e]], 1);
}

// single block, 1024 threads, 32 counts each; writes start[0..NN] and cursor
__global__ __launch_bounds__(1024) void scan_kernel(
    const int* __restrict__ counts, int* __restrict__ start, int* __restrict__ cursor)
{
    __shared__ int tmp[1024];
    int tid = threadIdx.x;
    int base = tid * 32;
    int local[32];
    int sum = 0;
    const int4* c4 = (const int4*)(counts + base);
#pragma unroll
    for (int q = 0; q < 8; q++) {
        int4 v = c4[q];
        local[q*4+0] = sum; sum += v.x;
        local[q*4+1] = sum; sum += v.y;
        local[q*4+2] = sum; sum += v.z;
        local[q*4+3] = sum; sum += v.w;
    }
    tmp[tid] = sum;
    __syncthreads();
    for (int off = 1; off < 1024; off <<= 1) {
        int v = 0;
        if (tid >= off) v = tmp[tid - off];
        __syncthreads();
        if (tid >= off) tmp[tid] += v;
        __syncthreads();
    }
    int excl = tmp[tid] - sum;
#pragma unroll
    for (int k = 0; k < 32; k++) {
        int s = excl + local[k];
        start[base + k] = s;
        cursor[base + k] = s;
    }
    if (tid == 1023) start[NN] = tmp[1023];
}

// ---------------- pack: fused fill + filter-MLP-layer-1 ----------------
// record (24 floats): [0:16)=h*rc, [16:20)=Yr, [20]=rc, [21]=j(bits), [22:24)=0
__global__ __launch_bounds__(256) void pack_kernel(
    const float* __restrict__ f_ij,     // (E,32)
    const float* __restrict__ rcut_ij,  // (E,)
    const float* __restrict__ Yr,       // (E,4)
    const int*   __restrict__ idx_i,
    const int*   __restrict__ idx_j,
    const float* __restrict__ mW1,      // (32,16)
    const float* __restrict__ mb1,      // (16,)
    int* __restrict__ cursor,
    float* __restrict__ epack)
{
    __shared__ float sW1[512];
    __shared__ float sb1[16];
    int t = threadIdx.x;
    for (int k = t; k < 512; k += 256) sW1[k] = mW1[k];
    if (t < 16) sb1[t] = mb1[t];
    __syncthreads();

    int e = blockIdx.x * 256 + t;
    float h[16];
#pragma unroll
    for (int f = 0; f < 16; f++) h[f] = sb1[f];
    const float4* frow = (const float4*)(f_ij + (size_t)e * 32);
#pragma unroll
    for (int rq = 0; rq < 8; rq++) {
        float4 fv = frow[rq];
        int r = rq * 4;
#pragma unroll
        for (int f = 0; f < 16; f++)
            h[f] += fv.x * sW1[(r+0)*16+f] + fv.y * sW1[(r+1)*16+f]
                  + fv.z * sW1[(r+2)*16+f] + fv.w * sW1[(r+3)*16+f];
    }
    float rc = rcut_ij[e];
#pragma unroll
    for (int f = 0; f < 16; f++) h[f] = sspf(h[f]) * rc;

    int i = idx_i[e];
    int j = idx_j[e];
    float4 y = ((const float4*)Yr)[e];
    int slot = atomicAdd(&cursor[i], 1);

    float* rec = epack + (size_t)slot * 24;
    float4* r4 = (float4*)rec;
#pragma unroll
    for (int q = 0; q < 4; q++) r4[q] = ((float4*)h)[q];
    r4[4] = y;
    rec[20] = rc;
    rec[21] = __int_as_float(j);
    rec[22] = 0.f;
    rec[23] = 0.f;
}

// ---------------- node embedding ----------------
__global__ __launch_bounds__(256) void embed_kernel(
    const float* __restrict__ x,
    const float* __restrict__ W1s,   // (64,16)
    const float* __restrict__ W1v,   // (32,16)
    float* __restrict__ embed)
{
    __shared__ float sWs[1024];
    __shared__ float sWv[512];
    int t = threadIdx.x;
    for (int k = t; k < 1024; k += 256) sWs[k] = W1s[k];
    for (int k = t; k < 512;  k += 256) sWv[k] = W1v[k];
    __syncthreads();

    int n = blockIdx.x * 256 + t;
    const float* xr = x + (size_t)n * 160;

    float s1[16];
#pragma unroll
    for (int f = 0; f < 16; f++) s1[f] = 0.f;
#pragma unroll
    for (int cq = 0; cq < 16; cq++) {
        float4 sv = ((const float4*)xr)[cq];
        int c = cq * 4;
#pragma unroll
        for (int f = 0; f < 16; f++) {
            s1[f] += sv.x * sWs[(c+0)*16+f] + sv.y * sWs[(c+1)*16+f]
                   + sv.z * sWs[(c+2)*16+f] + sv.w * sWs[(c+3)*16+f];
        }
    }

    float v1[48];
#pragma unroll
    for (int k = 0; k < 48; k++) v1[k] = 0.f;
#pragma unroll
    for (int q = 0; q < 24; q++) {
        float4 vv = ((const float4*)(xr + 64))[q];
        float vals[4] = {vv.x, vv.y, vv.z, vv.w};
#pragma unroll
        for (int u = 0; u < 4; u++) {
            int m = q * 4 + u;
            int c = m / 3, d = m % 3;
            float val = vals[u];
#pragma unroll
            for (int f = 0; f < 16; f++)
                v1[f*3+d] += val * sWv[c*16+f];
        }
    }

    float ob[64];
#pragma unroll
    for (int f = 0; f < 16; f++) ob[f] = s1[f] * 0.125f;
    const float is32 = 0.17677669529663688f;
#pragma unroll
    for (int k = 0; k < 48; k++) ob[16+k] = v1[k] * is32;

    float4* eo = (float4*)(embed + (size_t)n * 64);
#pragma unroll
    for (int q = 0; q < 16; q++) eo[q] = ((float4*)ob)[q];
}

// ---------------- node-centric aggregation ----------------
// 8 threads per node: eway = (sub>>2) in {0,1} splits edges, r = sub&3 gives f-block.
// acc layout per node: [0:16]=n0a, [16:32]=n0b, [32:80]=n1a, [80:128]=n1b
__global__ __launch_bounds__(256, 3) void nodeagg_kernel(
    const float* __restrict__ embed,   // (N,64)
    const float* __restrict__ epack,   // (E,24) CSR-ordered records
    const int*   __restrict__ start,   // (N+1,)
    const float* __restrict__ mW2,     // (16,96)
    const float* __restrict__ mb2,     // (96,)
    float* __restrict__ acc)           // (N,128)
{
    __shared__ float sW2[1024];        // sW2[f*64+c] = mW2[f*96+c]
    int t = threadIdx.x;
    for (int k = t; k < 1024; k += 256)
        sW2[k] = mW2[(k >> 6) * 96 + (k & 63)];
    __syncthreads();

    int gid = blockIdx.x * 256 + t;
    int node = gid >> 3;
    int sub = gid & 7;
    int eway = sub >> 2;
    int fb = (sub & 3) * 4;

    float b0a[4], b0b[4], b1a[4], b1b[4];
#pragma unroll
    for (int u = 0; u < 4; u++) {
        b0a[u] = mb2[fb+u];
        b0b[u] = mb2[16+fb+u];
        b1a[u] = mb2[32+fb+u];
        b1b[u] = mb2[48+fb+u];
    }

    float a0a[4] = {0,0,0,0};
    float a0b[4] = {0,0,0,0};
    float a1a[12], a1b[12];
#pragma unroll
    for (int k = 0; k < 12; k++) { a1a[k] = 0.f; a1b[k] = 0.f; }

    int s0 = start[node];
    int s1 = start[node+1];

    for (int q = s0 + eway; q < s1; q += 2) {
        const float* rec = epack + (size_t)q * 24;
        const float4* r4 = (const float4*)rec;
        float4 h0 = r4[0], h1 = r4[1], h2 = r4[2], h3 = r4[3];
        float4 y  = r4[4];
        float rc  = rec[20];
        int j = __float_as_int(rec[21]);

        const float* em = embed + (size_t)j * 64;
        float4 sj4 = *(const float4*)(em + fb);
        float4 vq0 = *(const float4*)(em + 16 + fb*3);
        float4 vq1 = *(const float4*)(em + 16 + fb*3 + 4);
        float4 vq2 = *(const float4*)(em + 16 + fb*3 + 8);

        float w0a[4], w0b[4], w1a[4], w1b[4];
#pragma unroll
        for (int u = 0; u < 4; u++) {
            w0a[u] = rc*b0a[u]; w0b[u] = rc*b0b[u];
            w1a[u] = rc*b1a[u]; w1b[u] = rc*b1b[u];
        }
        float h[16] = {h0.x,h0.y,h0.z,h0.w, h1.x,h1.y,h1.z,h1.w,
                       h2.x,h2.y,h2.z,h2.w, h3.x,h3.y,h3.z,h3.w};
#pragma unroll
        for (int f = 0; f < 16; f++) {
            float hf = h[f];
            const float* wr = sW2 + f*64;
#pragma unroll
            for (int u = 0; u < 4; u++) {
                w0a[u] += hf * wr[fb+u];
                w0b[u] += hf * wr[16+fb+u];
                w1a[u] += hf * wr[32+fb+u];
                w1b[u] += hf * wr[48+fb+u];
            }
        }

        float sj[4] = {sj4.x, sj4.y, sj4.z, sj4.w};
        float vj[12] = {vq0.x,vq0.y,vq0.z,vq0.w, vq1.x,vq1.y,vq1.z,vq1.w,
                        vq2.x,vq2.y,vq2.z,vq2.w};
#pragma unroll
        for (int u = 0; u < 4; u++) {
            float vx = vj[u*3+0], vy = vj[u*3+1], vz = vj[u*3+2];
            a0a[u] += sj[u] * y.x * w0a[u];
            a0b[u] += (vx*y.y + vy*y.z + vz*y.w) * w0b[u];
            float sw = sj[u] * w1a[u];
            a1a[u*3+0] += sw * y.y;
            a1a[u*3+1] += sw * y.z;
            a1a[u*3+2] += sw * y.w;
            float yw = y.x * w1b[u];
            a1b[u*3+0] += vx * yw;
            a1b[u*3+1] += vy * yw;
            a1b[u*3+2] += vz * yw;
        }
    }

    // combine the two edge-ways (lanes differing in bit 2 of sub)
#pragma unroll
    for (int u = 0; u < 4; u++) {
        a0a[u] += __shfl_xor(a0a[u], 4);
        a0b[u] += __shfl_xor(a0b[u], 4);
    }
#pragma unroll
    for (int k = 0; k < 12; k++) {
        a1a[k] += __shfl_xor(a1a[k], 4);
        a1b[k] += __shfl_xor(a1b[k], 4);
    }

    if (eway == 0) {
        const float is3 = 0.5773502691896258f;   // 1/sqrt(3)
        float* o = acc + (size_t)node * 128;
        float4 t0 = {a0a[0], a0a[1], a0a[2], a0a[3]};
        float4 t1 = {a0b[0]*is3, a0b[1]*is3, a0b[2]*is3, a0b[3]*is3};
        *(float4*)(o + fb) = t0;
        *(float4*)(o + 16 + fb) = t1;
#pragma unroll
        for (int qq = 0; qq < 3; qq++) {
            *(float4*)(o + 32 + fb*3 + qq*4) = ((float4*)a1a)[qq];
            *(float4*)(o + 80 + fb*3 + qq*4) = ((float4*)a1b)[qq];
        }
    }
}

// ---------------- node output ----------------
__global__ __launch_bounds__(256) void out_kernel(
    const float* __restrict__ acc,      // (N,128)
    const float* __restrict__ W2s,      // (32,64)
    const float* __restrict__ W2v,      // (32,32)
    const float* __restrict__ W3s,      // (64,64)
    const float* __restrict__ W3v,      // (32,32)
    float* __restrict__ out)            // (N,160)
{
    __shared__ float lds[4][288];
    int t = threadIdx.x;
    int wv = t >> 6, ln = t & 63;
    int n = blockIdx.x * 4 + wv;
    float* L = lds[wv];
    const float* a = acc + (size_t)n * 128;
    L[ln] = a[ln];
    L[64+ln] = a[64+ln];
    __syncthreads();

    const float is32 = 0.17677669529663688f;

    float s_acc = 0.f;
#pragma unroll
    for (int g = 0; g < 32; g++) s_acc += L[g] * W2s[g*64 + ln];
    float s2 = sspf(s_acc * is32);

    float v2a = 0.f, v2b = 0.f;
    int c1 = ln / 3, d1 = ln % 3;
    int o2i = ln + 64;
    int c2 = o2i / 3, d2 = o2i % 3;
#pragma unroll
    for (int f = 0; f < 32; f++) {
        v2a += L[32 + f*3 + d1] * W2v[f*32 + c1];
        if (ln < 32) v2b += L[32 + f*3 + d2] * W2v[f*32 + c2];
    }

    L[128 + ln] = s2;
    L[192 + ln] = v2a * is32;
    if (ln < 32) L[192 + 64 + ln] = v2b * is32;
    __syncthreads();

    float s3 = 0.f;
#pragma unroll
    for (int k = 0; k < 64; k++) s3 += L[128+k] * W3s[k*64 + ln];
    out[(size_t)n*160 + ln] = s3 * 0.125f;

    int e1 = ln / 3;
    float a1 = 0.f;
#pragma unroll
    for (int c = 0; c < 32; c++) a1 += L[192 + c*3 + d1] * W3v[c*32 + e1];
    out[(size_t)n*160 + 64 + ln] = a1 * is32;
    if (ln < 32) {
        int e2 = o2i / 3;
        float a2 = 0.f;
#pragma unroll
        for (int c = 0; c < 32; c++) a2 += L[192 + c*3 + d2] * W3v[c*32 + e2];
        out[(size_t)n*160 + 64 + o2i] = a2 * is32;
    }
}

extern "C" void kernel_launch(void* const* d_in, const int* in_sizes, int n_in,
                              void* d_out, int out_size, void* d_ws, size_t ws_size,
                              hipStream_t stream) {
    const float* x     = (const float*)d_in[0];
    const float* f_ij  = (const float*)d_in[1];
    const float* rcut  = (const float*)d_in[2];
    const float* Yr    = (const float*)d_in[3];
    const float* W1s   = (const float*)d_in[4];
    const float* W1v   = (const float*)d_in[5];
    const float* mW1   = (const float*)d_in[6];
    const float* mb1   = (const float*)d_in[7];
    const float* mW2   = (const float*)d_in[8];
    const float* mb2   = (const float*)d_in[9];
    const float* W2s   = (const float*)d_in[10];
    const float* W2v   = (const float*)d_in[11];
    const float* W3s   = (const float*)d_in[12];
    const float* W3v   = (const float*)d_in[13];
    const int*   idx_i = (const int*)d_in[14];
    const int*   idx_j = (const int*)d_in[15];
    float* out = (float*)d_out;

    // workspace layout (floats)
    float* fws   = (float*)d_ws;
    float* embed = fws;                                  // N*64
    float* acc   = embed + (size_t)NN * 64;              // N*128
    float* epack = acc   + (size_t)NN * 128;             // E*24
    int* ibase   = (int*)(epack + (size_t)NE * 24);
    int* counts  = ibase;                                // N
    int* start   = counts + NN;                          // N+1
    int* cursor  = start + NN + 1;                       // N

    hipMemsetAsync(counts, 0, (size_t)NN * sizeof(int), stream);
    hist_kernel<<<NE/256, 256, 0, stream>>>(idx_i, counts);
    scan_kernel<<<1, 1024, 0, stream>>>(counts, start, cursor);
    pack_kernel<<<NE/256, 256, 0, stream>>>(f_ij, rcut, Yr, idx_i, idx_j,
                                            mW1, mb1, cursor, epack);
    embed_kernel<<<NN/256, 256, 0, stream>>>(x, W1s, W1v, embed);
    nodeagg_kernel<<<(NN*8)/256, 256, 0, stream>>>(embed, epack, start, mW2, mb2, acc);
    out_kernel<<<NN/4, 256, 0, stream>>>(acc, W2s, W2v, W3s, W3v, out);
}

// Round 4
// 394.360 us; speedup vs baseline: 2.1793x; 2.1793x over previous
//
#include <hip/hip_runtime.h>
#include <math.h>

#define NN 32768
#define NE 524288

__device__ __forceinline__ float sspf(float x) {
    float r = fmaxf(x, 0.0f) + log1pf(expf(-fabsf(x)));
    return r - 0.69314718055994530942f;
}

// ---------------- CSR build ----------------
__global__ __launch_bounds__(256) void hist_kernel(
    const int* __restrict__ idx_i, int* __restrict__ counts)
{
    int e = blockIdx.x * 256 + threadIdx.x;
    atomicAdd(&counts[idx_i[e]], 1);
}

// single block, 1024 threads, 32 counts each; writes start[0..NN] and cursor
__global__ __launch_bounds__(1024) void scan_kernel(
    const int* __restrict__ counts, int* __restrict__ start, int* __restrict__ cursor)
{
    __shared__ int tmp[1024];
    int tid = threadIdx.x;
    int base = tid * 32;
    int local[32];
    int sum = 0;
    const int4* c4 = (const int4*)(counts + base);
#pragma unroll
    for (int q = 0; q < 8; q++) {
        int4 v = c4[q];
        local[q*4+0] = sum; sum += v.x;
        local[q*4+1] = sum; sum += v.y;
        local[q*4+2] = sum; sum += v.z;
        local[q*4+3] = sum; sum += v.w;
    }
    tmp[tid] = sum;
    __syncthreads();
    for (int off = 1; off < 1024; off <<= 1) {
        int v = 0;
        if (tid >= off) v = tmp[tid - off];
        __syncthreads();
        if (tid >= off) tmp[tid] += v;
        __syncthreads();
    }
    int excl = tmp[tid] - sum;
#pragma unroll
    for (int k = 0; k < 32; k++) {
        int s = excl + local[k];
        start[base + k] = s;
        cursor[base + k] = s;
    }
    if (tid == 1023) start[NN] = tmp[1023];
}

// ---------------- pack: fused fill + filter-MLP-layer-1 ----------------
// record (24 floats): [0:16)=h*rc, [16:20)=Yr, [20]=rc, [21]=j(bits), [22:24)=pad
__global__ __launch_bounds__(256) void pack_kernel(
    const float* __restrict__ f_ij,     // (E,32)
    const float* __restrict__ rcut_ij,  // (E,)
    const float* __restrict__ Yr,       // (E,4)
    const int*   __restrict__ idx_i,
    const int*   __restrict__ idx_j,
    const float* __restrict__ mW1,      // (32,16)
    const float* __restrict__ mb1,      // (16,)
    int* __restrict__ cursor,
    float* __restrict__ epack)
{
    __shared__ float sW1[512];
    __shared__ float sb1[16];
    int t = threadIdx.x;
    for (int k = t; k < 512; k += 256) sW1[k] = mW1[k];
    if (t < 16) sb1[t] = mb1[t];
    __syncthreads();

    int e = blockIdx.x * 256 + t;
    float h[16];
#pragma unroll
    for (int f = 0; f < 16; f++) h[f] = sb1[f];
    const float4* frow = (const float4*)(f_ij + (size_t)e * 32);
#pragma unroll
    for (int rq = 0; rq < 8; rq++) {
        float4 fv = frow[rq];
        int r = rq * 4;
#pragma unroll
        for (int f = 0; f < 16; f++)
            h[f] += fv.x * sW1[(r+0)*16+f] + fv.y * sW1[(r+1)*16+f]
                  + fv.z * sW1[(r+2)*16+f] + fv.w * sW1[(r+3)*16+f];
    }
    float rc = rcut_ij[e];
#pragma unroll
    for (int f = 0; f < 16; f++) h[f] = sspf(h[f]) * rc;

    int i = idx_i[e];
    int j = idx_j[e];
    float4 y = ((const float4*)Yr)[e];
    int slot = atomicAdd(&cursor[i], 1);

    float* rec = epack + (size_t)slot * 24;
    float4* r4 = (float4*)rec;
#pragma unroll
    for (int q = 0; q < 4; q++) r4[q] = ((float4*)h)[q];
    r4[4] = y;
    rec[20] = rc;
    rec[21] = __int_as_float(j);
    rec[22] = 0.f;
    rec[23] = 0.f;
}

// ---------------- node embedding ----------------
__global__ __launch_bounds__(256) void embed_kernel(
    const float* __restrict__ x,
    const float* __restrict__ W1s,   // (64,16)
    const float* __restrict__ W1v,   // (32,16)
    float* __restrict__ embed)
{
    __shared__ float sWs[1024];
    __shared__ float sWv[512];
    int t = threadIdx.x;
    for (int k = t; k < 1024; k += 256) sWs[k] = W1s[k];
    for (int k = t; k < 512;  k += 256) sWv[k] = W1v[k];
    __syncthreads();

    int n = blockIdx.x * 256 + t;
    const float* xr = x + (size_t)n * 160;

    float s1[16];
#pragma unroll
    for (int f = 0; f < 16; f++) s1[f] = 0.f;
#pragma unroll
    for (int cq = 0; cq < 16; cq++) {
        float4 sv = ((const float4*)xr)[cq];
        int c = cq * 4;
#pragma unroll
        for (int f = 0; f < 16; f++) {
            s1[f] += sv.x * sWs[(c+0)*16+f] + sv.y * sWs[(c+1)*16+f]
                   + sv.z * sWs[(c+2)*16+f] + sv.w * sWs[(c+3)*16+f];
        }
    }

    float v1[48];
#pragma unroll
    for (int k = 0; k < 48; k++) v1[k] = 0.f;
#pragma unroll
    for (int q = 0; q < 24; q++) {
        float4 vv = ((const float4*)(xr + 64))[q];
        float vals[4] = {vv.x, vv.y, vv.z, vv.w};
#pragma unroll
        for (int u = 0; u < 4; u++) {
            int m = q * 4 + u;
            int c = m / 3, d = m % 3;
            float val = vals[u];
#pragma unroll
            for (int f = 0; f < 16; f++)
                v1[f*3+d] += val * sWv[c*16+f];
        }
    }

    float ob[64];
#pragma unroll
    for (int f = 0; f < 16; f++) ob[f] = s1[f] * 0.125f;
    const float is32 = 0.17677669529663688f;
#pragma unroll
    for (int k = 0; k < 48; k++) ob[16+k] = v1[k] * is32;

    float4* eo = (float4*)(embed + (size_t)n * 64);
#pragma unroll
    for (int q = 0; q < 16; q++) eo[q] = ((float4*)ob)[q];
}

// ---------------- node-centric aggregation ----------------
// 16 threads per node; thread handles a single f. w-matmul fully partitioned
// (thread computes only its 4 w columns from its 64 register-resident weights).
// acc layout per node: [0:16]=n0a, [16:32]=n0b, [32:80]=n1a, [80:128]=n1b
__global__ __launch_bounds__(256) void nodeagg_kernel(
    const float* __restrict__ embed,   // (N,64)
    const float* __restrict__ epack,   // (E,24) CSR-ordered records
    const int*   __restrict__ start,   // (N+1,)
    const float* __restrict__ mW2,     // (16,96)
    const float* __restrict__ mb2,     // (96,)
    float* __restrict__ acc)           // (N,128)
{
    __shared__ float sW2[1024];        // sW2[k*64+c] = mW2[k*96+c], c<64
    int t = threadIdx.x;
    for (int k = t; k < 1024; k += 256)
        sW2[k] = mW2[(k >> 6) * 96 + (k & 63)];
    __syncthreads();

    int gid = blockIdx.x * 256 + t;
    int node = gid >> 4;
    int f = gid & 15;

    // preload this thread's 64 weight values into registers
    float wga[16], wgb[16], wgc[16], wgd[16];
#pragma unroll
    for (int k = 0; k < 16; k++) {
        wga[k] = sW2[k*64 + f];
        wgb[k] = sW2[k*64 + 16 + f];
        wgc[k] = sW2[k*64 + 32 + f];
        wgd[k] = sW2[k*64 + 48 + f];
    }
    float b0a = mb2[f], b0b = mb2[16+f], b1a = mb2[32+f], b1b = mb2[48+f];

    float aa = 0.f, ab = 0.f;
    float A1a0 = 0.f, A1a1 = 0.f, A1a2 = 0.f;
    float A1b0 = 0.f, A1b1 = 0.f, A1b2 = 0.f;

    int s0 = start[node];
    int s1 = start[node+1];

    for (int q = s0; q < s1; q++) {
        const float* rec = epack + (size_t)q * 24;
        const float4* r4 = (const float4*)rec;
        float4 h0 = r4[0], h1 = r4[1], h2 = r4[2], h3 = r4[3];
        float4 y  = r4[4];
        float rc  = rec[20];
        int j = __float_as_int(rec[21]);

        const float* em = embed + (size_t)j * 64;
        float sj = em[f];
        float vx = em[16 + f*3 + 0];
        float vy = em[16 + f*3 + 1];
        float vz = em[16 + f*3 + 2];

        float w0a = rc*b0a, w0b = rc*b0b, w1a = rc*b1a, w1b = rc*b1b;
        float h[16] = {h0.x,h0.y,h0.z,h0.w, h1.x,h1.y,h1.z,h1.w,
                       h2.x,h2.y,h2.z,h2.w, h3.x,h3.y,h3.z,h3.w};
#pragma unroll
        for (int k = 0; k < 16; k++) {
            w0a += h[k] * wga[k];
            w0b += h[k] * wgb[k];
            w1a += h[k] * wgc[k];
            w1b += h[k] * wgd[k];
        }

        aa += sj * y.x * w0a;
        ab += (vx*y.y + vy*y.z + vz*y.w) * w0b;
        float sw = sj * w1a;
        A1a0 += sw * y.y;
        A1a1 += sw * y.z;
        A1a2 += sw * y.w;
        float yw = y.x * w1b;
        A1b0 += vx * yw;
        A1b1 += vy * yw;
        A1b2 += vz * yw;
    }

    const float is3 = 0.5773502691896258f;   // 1/sqrt(3)
    float* o = acc + (size_t)node * 128;
    o[f] = aa;
    o[16 + f] = ab * is3;
    o[32 + f*3 + 0] = A1a0;
    o[32 + f*3 + 1] = A1a1;
    o[32 + f*3 + 2] = A1a2;
    o[80 + f*3 + 0] = A1b0;
    o[80 + f*3 + 1] = A1b1;
    o[80 + f*3 + 2] = A1b2;
}

// ---------------- node output ----------------
__global__ __launch_bounds__(256) void out_kernel(
    const float* __restrict__ acc,      // (N,128)
    const float* __restrict__ W2s,      // (32,64)
    const float* __restrict__ W2v,      // (32,32)
    const float* __restrict__ W3s,      // (64,64)
    const float* __restrict__ W3v,      // (32,32)
    float* __restrict__ out)            // (N,160)
{
    __shared__ float lds[4][288];
    int t = threadIdx.x;
    int wv = t >> 6, ln = t & 63;
    int n = blockIdx.x * 4 + wv;
    float* L = lds[wv];
    const float* a = acc + (size_t)n * 128;
    L[ln] = a[ln];
    L[64+ln] = a[64+ln];
    __syncthreads();

    const float is32 = 0.17677669529663688f;

    float s_acc = 0.f;
#pragma unroll
    for (int g = 0; g < 32; g++) s_acc += L[g] * W2s[g*64 + ln];
    float s2 = sspf(s_acc * is32);

    float v2a = 0.f, v2b = 0.f;
    int c1 = ln / 3, d1 = ln % 3;
    int o2i = ln + 64;
    int c2 = o2i / 3, d2 = o2i % 3;
#pragma unroll
    for (int fq = 0; fq < 32; fq++) {
        v2a += L[32 + fq*3 + d1] * W2v[fq*32 + c1];
        if (ln < 32) v2b += L[32 + fq*3 + d2] * W2v[fq*32 + c2];
    }

    L[128 + ln] = s2;
    L[192 + ln] = v2a * is32;
    if (ln < 32) L[192 + 64 + ln] = v2b * is32;
    __syncthreads();

    float s3 = 0.f;
#pragma unroll
    for (int k = 0; k < 64; k++) s3 += L[128+k] * W3s[k*64 + ln];
    out[(size_t)n*160 + ln] = s3 * 0.125f;

    float a1 = 0.f;
#pragma unroll
    for (int c = 0; c < 32; c++) a1 += L[192 + c*3 + d1] * W3v[c*32 + c1];
    out[(size_t)n*160 + 64 + ln] = a1 * is32;
    if (ln < 32) {
        float a2 = 0.f;
#pragma unroll
        for (int c = 0; c < 32; c++) a2 += L[192 + c*3 + d2] * W3v[c*32 + c2];
        out[(size_t)n*160 + 64 + o2i] = a2 * is32;
    }
}

extern "C" void kernel_launch(void* const* d_in, const int* in_sizes, int n_in,
                              void* d_out, int out_size, void* d_ws, size_t ws_size,
                              hipStream_t stream) {
    const float* x     = (const float*)d_in[0];
    const float* f_ij  = (const float*)d_in[1];
    const float* rcut  = (const float*)d_in[2];
    const float* Yr    = (const float*)d_in[3];
    const float* W1s   = (const float*)d_in[4];
    const float* W1v   = (const float*)d_in[5];
    const float* mW1   = (const float*)d_in[6];
    const float* mb1   = (const float*)d_in[7];
    const float* mW2   = (const float*)d_in[8];
    const float* mb2   = (const float*)d_in[9];
    const float* W2s   = (const float*)d_in[10];
    const float* W2v   = (const float*)d_in[11];
    const float* W3s   = (const float*)d_in[12];
    const float* W3v   = (const float*)d_in[13];
    const int*   idx_i = (const int*)d_in[14];
    const int*   idx_j = (const int*)d_in[15];
    float* out = (float*)d_out;

    // workspace layout (floats)
    float* fws   = (float*)d_ws;
    float* embed = fws;                                  // N*64
    float* acc   = embed + (size_t)NN * 64;              // N*128
    float* epack = acc   + (size_t)NN * 128;             // E*24
    int* ibase   = (int*)(epack + (size_t)NE * 24);
    int* counts  = ibase;                                // N
    int* start   = counts + NN;                          // N+1
    int* cursor  = start + NN + 1;                       // N

    hipMemsetAsync(counts, 0, (size_t)NN * sizeof(int), stream);
    hist_kernel<<<NE/256, 256, 0, stream>>>(idx_i, counts);
    scan_kernel<<<1, 1024, 0, stream>>>(counts, start, cursor);
    pack_kernel<<<NE/256, 256, 0, stream>>>(f_ij, rcut, Yr, idx_i, idx_j,
                                            mW1, mb1, cursor, epack);
    embed_kernel<<<NN/256, 256, 0, stream>>>(x, W1s, W1v, embed);
    nodeagg_kernel<<<(NN*16)/256, 256, 0, stream>>>(embed, epack, start, mW2, mb2, acc);
    out_kernel<<<NN/4, 256, 0, stream>>>(acc, W2s, W2v, W3s, W3v, out);
}

// Round 5
// 375.546 us; speedup vs baseline: 2.2885x; 1.0501x over previous
//
#include <hip/hip_runtime.h>
#include <math.h>

#define NN 32768
#define NE 524288

__device__ __forceinline__ float sspf(float x) {
    float r = fmaxf(x, 0.0f) + log1pf(expf(-fabsf(x)));
    return r - 0.69314718055994530942f;
}

// ---------------- CSR build ----------------
__global__ __launch_bounds__(256) void hist_kernel(
    const int* __restrict__ idx_i, int* __restrict__ counts)
{
    int e = blockIdx.x * 256 + threadIdx.x;
    atomicAdd(&counts[idx_i[e]], 1);
}

// single block, 1024 threads, 32 counts each; writes start[0..NN] and cursor
__global__ __launch_bounds__(1024) void scan_kernel(
    const int* __restrict__ counts, int* __restrict__ start, int* __restrict__ cursor)
{
    __shared__ int tmp[1024];
    int tid = threadIdx.x;
    int base = tid * 32;
    int local[32];
    int sum = 0;
    const int4* c4 = (const int4*)(counts + base);
#pragma unroll
    for (int q = 0; q < 8; q++) {
        int4 v = c4[q];
        local[q*4+0] = sum; sum += v.x;
        local[q*4+1] = sum; sum += v.y;
        local[q*4+2] = sum; sum += v.z;
        local[q*4+3] = sum; sum += v.w;
    }
    tmp[tid] = sum;
    __syncthreads();
    for (int off = 1; off < 1024; off <<= 1) {
        int v = 0;
        if (tid >= off) v = tmp[tid - off];
        __syncthreads();
        if (tid >= off) tmp[tid] += v;
        __syncthreads();
    }
    int excl = tmp[tid] - sum;
#pragma unroll
    for (int k = 0; k < 32; k++) {
        int s = excl + local[k];
        start[base + k] = s;
        cursor[base + k] = s;
    }
    if (tid == 1023) start[NN] = tmp[1023];
}

// ---------------- pack: fused fill + filter-MLP-layer-1 ----------------
// record (24 floats): [0:16)=h*rc, [16:20)=Yr, [20]=rc, [21]=j(bits), [22:24)=pad
__global__ __launch_bounds__(256) void pack_kernel(
    const float* __restrict__ f_ij,     // (E,32)
    const float* __restrict__ rcut_ij,  // (E,)
    const float* __restrict__ Yr,       // (E,4)
    const int*   __restrict__ idx_i,
    const int*   __restrict__ idx_j,
    const float* __restrict__ mW1,      // (32,16)
    const float* __restrict__ mb1,      // (16,)
    int* __restrict__ cursor,
    float* __restrict__ epack)
{
    __shared__ float sW1[512];
    __shared__ float sb1[16];
    int t = threadIdx.x;
    for (int k = t; k < 512; k += 256) sW1[k] = mW1[k];
    if (t < 16) sb1[t] = mb1[t];
    __syncthreads();

    int e = blockIdx.x * 256 + t;
    float h[16];
#pragma unroll
    for (int f = 0; f < 16; f++) h[f] = sb1[f];
    const float4* frow = (const float4*)(f_ij + (size_t)e * 32);
#pragma unroll
    for (int rq = 0; rq < 8; rq++) {
        float4 fv = frow[rq];
        int r = rq * 4;
#pragma unroll
        for (int f = 0; f < 16; f++)
            h[f] += fv.x * sW1[(r+0)*16+f] + fv.y * sW1[(r+1)*16+f]
                  + fv.z * sW1[(r+2)*16+f] + fv.w * sW1[(r+3)*16+f];
    }
    float rc = rcut_ij[e];
#pragma unroll
    for (int f = 0; f < 16; f++) h[f] = sspf(h[f]) * rc;

    int i = idx_i[e];
    int j = idx_j[e];
    float4 y = ((const float4*)Yr)[e];
    int slot = atomicAdd(&cursor[i], 1);

    float* rec = epack + (size_t)slot * 24;
    float4* r4 = (float4*)rec;
#pragma unroll
    for (int q = 0; q < 4; q++) r4[q] = ((float4*)h)[q];
    r4[4] = y;
    rec[20] = rc;
    rec[21] = __int_as_float(j);
    rec[22] = 0.f;
    rec[23] = 0.f;
}

// ---------------- node embedding ----------------
// planar output layout: [0:16)=s1, [16:32)=v1x, [32:48)=v1y, [48:64)=v1z
__global__ __launch_bounds__(256) void embed_kernel(
    const float* __restrict__ x,
    const float* __restrict__ W1s,   // (64,16)
    const float* __restrict__ W1v,   // (32,16)
    float* __restrict__ embed)
{
    __shared__ float sWs[1024];
    __shared__ float sWv[512];
    int t = threadIdx.x;
    for (int k = t; k < 1024; k += 256) sWs[k] = W1s[k];
    for (int k = t; k < 512;  k += 256) sWv[k] = W1v[k];
    __syncthreads();

    int n = blockIdx.x * 256 + t;
    const float* xr = x + (size_t)n * 160;

    float s1[16];
#pragma unroll
    for (int f = 0; f < 16; f++) s1[f] = 0.f;
#pragma unroll
    for (int cq = 0; cq < 16; cq++) {
        float4 sv = ((const float4*)xr)[cq];
        int c = cq * 4;
#pragma unroll
        for (int f = 0; f < 16; f++) {
            s1[f] += sv.x * sWs[(c+0)*16+f] + sv.y * sWs[(c+1)*16+f]
                   + sv.z * sWs[(c+2)*16+f] + sv.w * sWs[(c+3)*16+f];
        }
    }

    float v1[48];
#pragma unroll
    for (int k = 0; k < 48; k++) v1[k] = 0.f;
#pragma unroll
    for (int q = 0; q < 24; q++) {
        float4 vv = ((const float4*)(xr + 64))[q];
        float vals[4] = {vv.x, vv.y, vv.z, vv.w};
#pragma unroll
        for (int u = 0; u < 4; u++) {
            int m = q * 4 + u;
            int c = m / 3, d = m % 3;
            float val = vals[u];
#pragma unroll
            for (int f = 0; f < 16; f++)
                v1[f*3+d] += val * sWv[c*16+f];
        }
    }

    float ob[64];
    const float is32 = 0.17677669529663688f;
#pragma unroll
    for (int f = 0; f < 16; f++) {
        ob[f]      = s1[f] * 0.125f;
        ob[16 + f] = v1[f*3+0] * is32;
        ob[32 + f] = v1[f*3+1] * is32;
        ob[48 + f] = v1[f*3+2] * is32;
    }

    float4* eo = (float4*)(embed + (size_t)n * 64);
#pragma unroll
    for (int q = 0; q < 16; q++) eo[q] = ((float4*)ob)[q];
}

// ---------------- node-centric aggregation ----------------
// 16 threads per node; thread handles a single f. w-matmul fully partitioned.
// acc planar layout per node:
// [0:16)=n0a, [16:32)=n0b, [32:48)=n1a_x, [48:64)=n1a_y, [64:80)=n1a_z,
// [80:96)=n1b_x, [96:112)=n1b_y, [112:128)=n1b_z
__global__ __launch_bounds__(256) void nodeagg_kernel(
    const float* __restrict__ embed,   // (N,64) planar
    const float* __restrict__ epack,   // (E,24) CSR-ordered records
    const int*   __restrict__ start,   // (N+1,)
    const float* __restrict__ mW2,     // (16,96)
    const float* __restrict__ mb2,     // (96,)
    float* __restrict__ acc)           // (N,128) planar
{
    __shared__ float sW2[1024];        // sW2[k*64+c] = mW2[k*96+c], c<64
    int t = threadIdx.x;
    for (int k = t; k < 1024; k += 256)
        sW2[k] = mW2[(k >> 6) * 96 + (k & 63)];
    __syncthreads();

    int gid = blockIdx.x * 256 + t;
    int node = gid >> 4;
    int f = gid & 15;

    float wga[16], wgb[16], wgc[16], wgd[16];
#pragma unroll
    for (int k = 0; k < 16; k++) {
        wga[k] = sW2[k*64 + f];
        wgb[k] = sW2[k*64 + 16 + f];
        wgc[k] = sW2[k*64 + 32 + f];
        wgd[k] = sW2[k*64 + 48 + f];
    }
    float b0a = mb2[f], b0b = mb2[16+f], b1a = mb2[32+f], b1b = mb2[48+f];

    float aa = 0.f, ab = 0.f;
    float A1a0 = 0.f, A1a1 = 0.f, A1a2 = 0.f;
    float A1b0 = 0.f, A1b1 = 0.f, A1b2 = 0.f;

    int s0 = start[node];
    int s1 = start[node+1];

    for (int q = s0; q < s1; q++) {
        const float* rec = epack + (size_t)q * 24;
        const float4* r4 = (const float4*)rec;
        float4 h0 = r4[0], h1 = r4[1], h2 = r4[2], h3 = r4[3];
        float4 y  = r4[4];
        float rc  = rec[20];
        int j = __float_as_int(rec[21]);

        const float* em = embed + (size_t)j * 64;
        float sj = em[f];
        float vx = em[16 + f];
        float vy = em[32 + f];
        float vz = em[48 + f];

        float w0a = rc*b0a, w0b = rc*b0b, w1a = rc*b1a, w1b = rc*b1b;
        float h[16] = {h0.x,h0.y,h0.z,h0.w, h1.x,h1.y,h1.z,h1.w,
                       h2.x,h2.y,h2.z,h2.w, h3.x,h3.y,h3.z,h3.w};
#pragma unroll
        for (int k = 0; k < 16; k++) {
            w0a += h[k] * wga[k];
            w0b += h[k] * wgb[k];
            w1a += h[k] * wgc[k];
            w1b += h[k] * wgd[k];
        }

        aa += sj * y.x * w0a;
        ab += (vx*y.y + vy*y.z + vz*y.w) * w0b;
        float sw = sj * w1a;
        A1a0 += sw * y.y;
        A1a1 += sw * y.z;
        A1a2 += sw * y.w;
        float yw = y.x * w1b;
        A1b0 += vx * yw;
        A1b1 += vy * yw;
        A1b2 += vz * yw;
    }

    const float is3 = 0.5773502691896258f;   // 1/sqrt(3)
    float* o = acc + (size_t)node * 128;
    o[f]       = aa;
    o[16 + f]  = ab * is3;
    o[32 + f]  = A1a0;
    o[48 + f]  = A1a1;
    o[64 + f]  = A1a2;
    o[80 + f]  = A1b0;
    o[96 + f]  = A1b1;
    o[112 + f] = A1b2;
}

// ---------------- node output ----------------
// 512 blocks x 256 threads; weights staged in LDS; each wave processes 16 nodes.
__global__ __launch_bounds__(256) void out_kernel(
    const float* __restrict__ acc,      // (N,128) planar
    const float* __restrict__ W2s,      // (32,64)
    const float* __restrict__ W2v,      // (32,32)
    const float* __restrict__ W3s,      // (64,64)
    const float* __restrict__ W3v,      // (32,32)
    float* __restrict__ out)            // (N,160)
{
    __shared__ float sW2s[2048];
    __shared__ float sW2v[1024];
    __shared__ float sW3s[4096];
    __shared__ float sW3v[1024];
    __shared__ float Lbuf[4][288];
    int t = threadIdx.x;
    for (int k = t; k < 2048; k += 256) sW2s[k] = W2s[k];
    for (int k = t; k < 1024; k += 256) sW2v[k] = W2v[k];
    for (int k = t; k < 4096; k += 256) sW3s[k] = W3s[k];
    for (int k = t; k < 1024; k += 256) sW3v[k] = W3v[k];
    __syncthreads();

    int wv = t >> 6, ln = t & 63;
    float* L = Lbuf[wv];
    const float is32 = 0.17677669529663688f;

    int c1 = ln / 3, d1 = ln % 3;
    int o2i = 64 + ln;
    int c2 = o2i / 3, d2 = o2i % 3;

    for (int it = 0; it < 16; it++) {
        int n = blockIdx.x * 64 + it * 4 + wv;
        const float* a = acc + (size_t)n * 128;
        float2 av = ((const float2*)a)[ln];
        ((float2*)L)[ln] = av;
        __syncthreads();

        // s2[ln] = ssp( n0 . W2s[:,ln] * is32 ), n0 = L[0:32]
        float s_acc = 0.f;
#pragma unroll
        for (int g = 0; g < 32; g++) s_acc += L[g] * sW2s[g*64 + ln];
        float s2 = sspf(s_acc * is32);

        // v2 for o=ln (c1,d1) and o=64+ln (c2,d2, ln<32)
        float v2a = 0.f, v2b = 0.f;
        int ba1 = 32 + d1*16, bb1 = 80 + d1*16;
        int ba2 = 32 + d2*16, bb2 = 80 + d2*16;
#pragma unroll
        for (int f = 0; f < 16; f++) {
            v2a += L[ba1+f] * sW2v[f*32 + c1];
            v2a += L[bb1+f] * sW2v[(16+f)*32 + c1];
            if (ln < 32) {
                v2b += L[ba2+f] * sW2v[f*32 + c2];
                v2b += L[bb2+f] * sW2v[(16+f)*32 + c2];
            }
        }

        L[128 + ln] = s2;
        L[192 + ln] = v2a * is32;
        if (ln < 32) L[192 + 64 + ln] = v2b * is32;
        __syncthreads();

        // s3
        float s3 = 0.f;
#pragma unroll
        for (int k = 0; k < 64; k++) s3 += L[128+k] * sW3s[k*64 + ln];
        out[(size_t)n*160 + ln] = s3 * 0.125f;

        // v3 (v2 stored interleaved at o=c*3+d)
        float a1 = 0.f;
#pragma unroll
        for (int c = 0; c < 32; c++) a1 += L[192 + c*3 + d1] * sW3v[c*32 + c1];
        out[(size_t)n*160 + 64 + ln] = a1 * is32;
        if (ln < 32) {
            float a2 = 0.f;
#pragma unroll
            for (int c = 0; c < 32; c++) a2 += L[192 + c*3 + d2] * sW3v[c*32 + c2];
            out[(size_t)n*160 + 64 + o2i] = a2 * is32;
        }
        __syncthreads();
    }
}

extern "C" void kernel_launch(void* const* d_in, const int* in_sizes, int n_in,
                              void* d_out, int out_size, void* d_ws, size_t ws_size,
                              hipStream_t stream) {
    const float* x     = (const float*)d_in[0];
    const float* f_ij  = (const float*)d_in[1];
    const float* rcut  = (const float*)d_in[2];
    const float* Yr    = (const float*)d_in[3];
    const float* W1s   = (const float*)d_in[4];
    const float* W1v   = (const float*)d_in[5];
    const float* mW1   = (const float*)d_in[6];
    const float* mb1   = (const float*)d_in[7];
    const float* mW2   = (const float*)d_in[8];
    const float* mb2   = (const float*)d_in[9];
    const float* W2s   = (const float*)d_in[10];
    const float* W2v   = (const float*)d_in[11];
    const float* W3s   = (const float*)d_in[12];
    const float* W3v   = (const float*)d_in[13];
    const int*   idx_i = (const int*)d_in[14];
    const int*   idx_j = (const int*)d_in[15];
    float* out = (float*)d_out;

    // workspace layout (floats)
    float* fws   = (float*)d_ws;
    float* embed = fws;                                  // N*64
    float* acc   = embed + (size_t)NN * 64;              // N*128
    float* epack = acc   + (size_t)NN * 128;             // E*24
    int* ibase   = (int*)(epack + (size_t)NE * 24);
    int* counts  = ibase;                                // N
    int* start   = counts + NN;                          // N+1
    int* cursor  = start + NN + 1;                       // N

    hipMemsetAsync(counts, 0, (size_t)NN * sizeof(int), stream);
    hist_kernel<<<NE/256, 256, 0, stream>>>(idx_i, counts);
    scan_kernel<<<1, 1024, 0, stream>>>(counts, start, cursor);
    pack_kernel<<<NE/256, 256, 0, stream>>>(f_ij, rcut, Yr, idx_i, idx_j,
                                            mW1, mb1, cursor, epack);
    embed_kernel<<<NN/256, 256, 0, stream>>>(x, W1s, W1v, embed);
    nodeagg_kernel<<<(NN*16)/256, 256, 0, stream>>>(embed, epack, start, mW2, mb2, acc);
    out_kernel<<<512, 256, 0, stream>>>(acc, W2s, W2v, W3s, W3v, out);
}